// Round 1
// baseline (4000.462 us; speedup 1.0000x reference)
//
#include <hip/hip_runtime.h>
#include <hip/hip_bf16.h>

typedef __attribute__((ext_vector_type(8))) short short8;     // 8 bf16 = 4 VGPR MFMA frag
typedef __attribute__((ext_vector_type(16))) float f32x16;    // 32x32 acc
typedef __attribute__((ext_vector_type(4))) float f32x4;      // 16x16 acc

#define HID 512
#define BT 32
#define OUTN 12

static __device__ __forceinline__ ushort f2bf(float f) {
    union { float f; uint u; } v; v.f = f;
    uint r = v.u + 0x7FFF + ((v.u >> 16) & 1);   // RNE
    return (ushort)(r >> 16);
}
static __device__ __forceinline__ float bf2f(ushort h) {
    union { float f; uint u; } v; v.u = ((uint)h) << 16; return v.f;
}

// ---- pack H_w (fp32 [512][512], u[n] = sum_k z[k]*H[n][k]) into bf16 hi/lo
// B-fragment stream order for v_mfma_f32_32x32x16_bf16:
//   idx = (((wnf*32 + ks)*64 + l)*8 + j)
//   element = H[n = wnf*32 + (l&31)][k = ks*16 + (l>>5)*8 + j]
__global__ void pack_h(const float* __restrict__ Hw,
                       ushort* __restrict__ hi, ushort* __restrict__ lo) {
    int t = blockIdx.x * blockDim.x + threadIdx.x;   // 0..32767
    int l   = t & 63;
    int ks  = (t >> 6) & 31;
    int wnf = t >> 11;                               // 0..15
    int n  = wnf * 32 + (l & 31);
    int k0 = ks * 16 + (l >> 5) * 8;
    int base = t * 8;
#pragma unroll
    for (int j = 0; j < 8; ++j) {
        float f = Hw[n * HID + k0 + j];
        ushort h = f2bf(f);
        hi[base + j] = h;
        lo[base + j] = f2bf(f - bf2f(h));
    }
}

// ---- pack O_w (fp32 [12][512]) into bf16, N padded to 16, for 16x16x32:
//   idx = ((ks*64 + l)*8 + j); element = O[col = l&15][k = ks*32 + (l>>4)*8 + j]
__global__ void pack_o(const float* __restrict__ Ow, ushort* __restrict__ op) {
    int t = blockIdx.x * blockDim.x + threadIdx.x;   // 0..1023
    int l  = t & 63;
    int ks = t >> 6;                                 // 0..15
    int col = l & 15;
    int k0  = ks * 32 + (l >> 4) * 8;
    int base = t * 8;
#pragma unroll
    for (int j = 0; j < 8; ++j) {
        float f = (col < OUTN) ? Ow[col * HID + k0 + j] : 0.0f;
        op[base + j] = f2bf(f);
    }
}

// z LDS layout: [m][k] bf16, row pitch 1024B, XOR swizzle on byte offset
static __device__ __forceinline__ int zoff(int m, int kbyte) {
    return m * 1024 + (kbyte ^ ((m & 15) << 4));
}

__launch_bounds__(512, 2)
__global__ void ctrnn_kernel(const float* __restrict__ x,
                             const int*   __restrict__ Tp,
                             const float* __restrict__ Iw,
                             const float* __restrict__ v,
                             const float* __restrict__ mb,
                             const ushort* __restrict__ Hhi,
                             const ushort* __restrict__ Hlo,
                             const ushort* __restrict__ Op,
                             float* __restrict__ out) {
    __shared__ ushort zhi[BT * HID];     // 32 KB
    __shared__ ushort zlo[BT * HID];     // 32 KB
    __shared__ uint4  lds_pad[2048];     // 32 KB -> 96 KB total: forces 1 block/CU

    const int T   = Tp[0];
    const int tid = threadIdx.x;
    const int l   = tid & 63;
    const int w   = tid >> 6;            // wave 0..7; owns N cols [w*64, w*64+64)
    const int b0  = blockIdx.x * BT;

    if (T == -123456) ((uint*)lds_pad)[tid] = 0;   // keep pad allocated

    // zero z state (z_0 = 0)
    {
        uint* p = (uint*)zhi;
        uint* q = (uint*)zlo;
#pragma unroll
        for (int i = 0; i < (BT * HID / 2) / 512; ++i) {
            p[tid + i * 512] = 0;
            q[tid + i * 512] = 0;
        }
    }

    // drive fragments (fp32, exact): drive[m][n] = x[b0+m]*Iw[n] + v[n]
    f32x16 drv[2];
#pragma unroll
    for (int nf = 0; nf < 2; ++nf) {
        int n = w * 64 + nf * 32 + (l & 31);
        float iw = Iw[n], vv = v[n];
#pragma unroll
        for (int r = 0; r < 16; ++r) {
            int mm = (r & 3) + 8 * (r >> 2) + 4 * (l >> 5);
            drv[nf][r] = x[b0 + mm] * iw + vv;
        }
    }

    // output bias frag (waves 0,1), broadcast over the 4 acc rows
    float mbias = 0.f;
    if (w < 2) {
        int col = l & 15;
        if (col < OUTN) mbias = mb[col];
    }

    // per-wave packed-H bases (ushort units): ((w*2+nf)*32 + ks)*512 + l*8
    const ushort* h0h = Hhi + (w * 2 + 0) * 32 * 512 + l * 8;
    const ushort* h0l = Hlo + (w * 2 + 0) * 32 * 512 + l * 8;
    const ushort* h1h = Hhi + (w * 2 + 1) * 32 * 512 + l * 8;
    const ushort* h1l = Hlo + (w * 2 + 1) * 32 * 512 + l * 8;

    // A-frag addressing (32x32x16): row = l&31, k = ks*16 + (l>>5)*8
    const int am    = l & 31;
    const int abase = am * 1024;
    const int axor  = (am & 15) << 4;
    const int akb   = (l >> 5) * 16;

    __syncthreads();

    for (int t = 0; t < T; ++t) {
        // ---- phase 1: u = drive + Hhi*zhi + Hhi*zlo + Hlo*zhi
        f32x16 acc0 = drv[0];
        f32x16 acc1 = drv[1];
#pragma unroll 8
        for (int ks = 0; ks < 32; ++ks) {
            int off = abase + ((ks * 32 + akb) ^ axor);
            short8 ah = *(const short8*)((const char*)zhi + off);
            short8 al = *(const short8*)((const char*)zlo + off);
            short8 b0h = *(const short8*)(h0h + ks * 512);
            short8 b0l = *(const short8*)(h0l + ks * 512);
            short8 b1h = *(const short8*)(h1h + ks * 512);
            short8 b1l = *(const short8*)(h1l + ks * 512);
            acc0 = __builtin_amdgcn_mfma_f32_32x32x16_bf16(ah, b0h, acc0, 0, 0, 0);
            acc0 = __builtin_amdgcn_mfma_f32_32x32x16_bf16(al, b0h, acc0, 0, 0, 0);
            acc0 = __builtin_amdgcn_mfma_f32_32x32x16_bf16(ah, b0l, acc0, 0, 0, 0);
            acc1 = __builtin_amdgcn_mfma_f32_32x32x16_bf16(ah, b1h, acc1, 0, 0, 0);
            acc1 = __builtin_amdgcn_mfma_f32_32x32x16_bf16(al, b1h, acc1, 0, 0, 0);
            acc1 = __builtin_amdgcn_mfma_f32_32x32x16_bf16(ah, b1l, acc1, 0, 0, 0);
        }
        __syncthreads();   // all reads of z_{t-1} done

        // ---- phase 2: z = tanh(u), split hi/lo, write to LDS
#pragma unroll
        for (int nf = 0; nf < 2; ++nf) {
            f32x16 a = nf ? acc1 : acc0;
            int kb = (w * 64 + nf * 32 + (l & 31)) * 2;   // k-byte = n*2
#pragma unroll
            for (int r = 0; r < 16; ++r) {
                int mm = (r & 3) + 8 * (r >> 2) + 4 * (l >> 5);
                // tanh(u) = 1 - 2/(e^{2u}+1); |u| <~ 25 so no overflow
                float e2 = __expf(2.0f * a[r]);
                float z  = 1.0f - __fdividef(2.0f, e2 + 1.0f);
                ushort h = f2bf(z);
                ushort lo_ = f2bf(z - bf2f(h));
                int off = zoff(mm, kb);
                *(ushort*)((char*)zhi + off) = h;
                *(ushort*)((char*)zlo + off) = lo_;
            }
        }
        __syncthreads();   // new z visible

        // ---- phase 3 (waves 0,1): y = sigmoid(z*O^T + m), store [B][T][12]
        if (w < 2) {
            f32x4 oacc = { mbias, mbias, mbias, mbias };
            int om    = w * 16 + (l & 15);
            int obase = om * 1024;
            int oxor  = (om & 15) << 4;
            int okb   = (l >> 4) * 16;
#pragma unroll
            for (int ks = 0; ks < 16; ++ks) {
                int off = obase + ((ks * 64 + okb) ^ oxor);
                short8 a  = *(const short8*)((const char*)zhi + off);
                short8 ob = *(const short8*)(Op + ks * 512 + l * 8);
                oacc = __builtin_amdgcn_mfma_f32_16x16x32_bf16(a, ob, oacc, 0, 0, 0);
            }
            int col = l & 15;
            if (col < OUTN) {
#pragma unroll
                for (int r = 0; r < 4; ++r) {
                    int mm = w * 16 + (l >> 4) * 4 + r;
                    float y = __fdividef(1.0f, 1.0f + __expf(-oacc[r]));
                    out[((size_t)(b0 + mm) * T + t) * OUTN + col] = y;
                }
            }
        }
    }
}

extern "C" void kernel_launch(void* const* d_in, const int* in_sizes, int n_in,
                              void* d_out, int out_size, void* d_ws, size_t ws_size,
                              hipStream_t stream) {
    const float* x  = (const float*)d_in[0];
    const int*   T  = (const int*)d_in[1];
    const float* Iw = (const float*)d_in[2];
    const float* Hw = (const float*)d_in[3];
    const float* Ow = (const float*)d_in[4];
    const float* v  = (const float*)d_in[5];
    const float* m  = (const float*)d_in[6];
    float* out = (float*)d_out;

    ushort* Hhi = (ushort*)d_ws;
    ushort* Hlo = Hhi + HID * HID;
    ushort* Op  = Hlo + HID * HID;   // 16*64*8 = 8192 ushorts

    pack_h<<<dim3(128), dim3(256), 0, stream>>>(Hw, Hhi, Hlo);
    pack_o<<<dim3(4), dim3(256), 0, stream>>>(Ow, Op);
    ctrnn_kernel<<<dim3(256), dim3(512), 0, stream>>>(x, T, Iw, v, m, Hhi, Hlo, Op, out);
}